// Round 1
// baseline (1353.372 us; speedup 1.0000x reference)
//
#include <hip/hip_runtime.h>
#include <math.h>

#define D_MODEL 1024
#define NHEAD 16
#define HEAD_DIM 64
#define BATCH 2
#define SEQ 1024
#define ROWS (BATCH * SEQ)   // 2048

// ---------------------------------------------------------------------------
// GEMM: C[i][j] = act( sum_k A[i][k] * B[j][k] )
// A: (M x K) row-major, B: (N x K) row-major, C: (M x N) row-major
// 64x64 block tile, BK=16, 256 threads, 4x4 microtile per thread.
// ACT: 0 = identity, 1 = silu
// ---------------------------------------------------------------------------
template <int ACT>
__global__ __launch_bounds__(256) void gemm_bt(const float* __restrict__ A,
                                               const float* __restrict__ B,
                                               float* __restrict__ C,
                                               int M, int N, int K) {
    // +4 pad: row stride 68 floats = 272B (16B-aligned, breaks pow2 conflicts)
    __shared__ __align__(16) float As[16][68];
    __shared__ __align__(16) float Bs[16][68];

    const int tid = threadIdx.x;
    const int tx = tid & 15;       // 0..15  -> column group
    const int ty = tid >> 4;       // 0..15  -> row group
    const int row0 = blockIdx.y * 64;
    const int col0 = blockIdx.x * 64;

    // loader mapping: 64 rows x 4 float4s per k-slab
    const int lrow = tid >> 2;          // 0..63
    const int lk   = (tid & 3) * 4;     // 0,4,8,12

    float acc[4][4] = {};

    for (int k0 = 0; k0 < K; k0 += 16) {
        float4 av = *(const float4*)&A[(size_t)(row0 + lrow) * K + k0 + lk];
        float4 bv = *(const float4*)&B[(size_t)(col0 + lrow) * K + k0 + lk];
        As[lk + 0][lrow] = av.x; As[lk + 1][lrow] = av.y;
        As[lk + 2][lrow] = av.z; As[lk + 3][lrow] = av.w;
        Bs[lk + 0][lrow] = bv.x; Bs[lk + 1][lrow] = bv.y;
        Bs[lk + 2][lrow] = bv.z; Bs[lk + 3][lrow] = bv.w;
        __syncthreads();
#pragma unroll
        for (int kk = 0; kk < 16; ++kk) {
            float4 a = *(const float4*)&As[kk][ty * 4];
            float4 b = *(const float4*)&Bs[kk][tx * 4];
            float ar[4] = {a.x, a.y, a.z, a.w};
            float br[4] = {b.x, b.y, b.z, b.w};
#pragma unroll
            for (int i = 0; i < 4; ++i)
#pragma unroll
                for (int j = 0; j < 4; ++j) acc[i][j] += ar[i] * br[j];
        }
        __syncthreads();
    }

#pragma unroll
    for (int i = 0; i < 4; ++i) {
        float4 o;
        float v0 = acc[i][0], v1 = acc[i][1], v2 = acc[i][2], v3 = acc[i][3];
        if (ACT == 1) {  // silu
            v0 = v0 / (1.f + expf(-v0));
            v1 = v1 / (1.f + expf(-v1));
            v2 = v2 / (1.f + expf(-v2));
            v3 = v3 / (1.f + expf(-v3));
        }
        o.x = v0; o.y = v1; o.z = v2; o.w = v3;
        *(float4*)&C[(size_t)(row0 + ty * 4 + i) * N + col0 + tx * 4] = o;
    }
}

// ---------------------------------------------------------------------------
// beta = 2*sigmoid(x @ Wb^T)  : (ROWS, NHEAD). One wave per row.
// ---------------------------------------------------------------------------
__global__ __launch_bounds__(256) void beta_kernel(const float* __restrict__ x,
                                                   const float* __restrict__ Wb,
                                                   float* __restrict__ beta) {
    const int wave = blockIdx.x * 4 + (threadIdx.x >> 6);  // row
    const int lane = threadIdx.x & 63;
    const float* xr = x + (size_t)wave * D_MODEL;
    float xv[16];
#pragma unroll
    for (int j = 0; j < 16; ++j) xv[j] = xr[lane + 64 * j];
    for (int n = 0; n < NHEAD; ++n) {
        const float* wr = Wb + (size_t)n * D_MODEL;
        float s = 0.f;
#pragma unroll
        for (int j = 0; j < 16; ++j) s += xv[j] * wr[lane + 64 * j];
#pragma unroll
        for (int off = 32; off; off >>= 1) s += __shfl_xor(s, off);
        if (lane == 0) beta[(size_t)wave * NHEAD + n] = 2.f / (1.f + expf(-s));
    }
}

// ---------------------------------------------------------------------------
// L2-normalize q and k per (row, head) over HEAD_DIM=64. One wave per (row,head,tensor).
// ---------------------------------------------------------------------------
__global__ __launch_bounds__(256) void norm_qk(float* __restrict__ Q,
                                               float* __restrict__ Kp) {
    const int TOT = ROWS * NHEAD;  // 32768
    int wave = blockIdx.x * 4 + (threadIdx.x >> 6);
    const int lane = threadIdx.x & 63;
    float* T = (wave < TOT) ? Q : Kp;
    int w = (wave < TOT) ? wave : wave - TOT;
    float* p = T + (size_t)(w >> 4) * D_MODEL + (size_t)(w & 15) * HEAD_DIM;
    float v = p[lane];
    float ss = v * v;
#pragma unroll
    for (int off = 32; off; off >>= 1) ss += __shfl_xor(ss, off);
    p[lane] = v / (sqrtf(ss) + 1e-6f);
}

// ---------------------------------------------------------------------------
// Sequential delta-rule scan. One block per (b, head). 256 threads.
// Thread t: r = t>>2 (0..63), g = t&3 (0..3).
// Owns M[r][16g..16g+16) and MT[r][16g..16g+16) (MT = M transposed).
// Per step (strictly causal — out/retrieved read M before update):
//   out[d]  = sum_h q[h]*M[h][d]  = sum_h MT[d][h]*q[h]
//   retr[h] = sum_d M[h][d]*k[d]
//   delta   = v - retr;  M[h][d] += beta*k[h]*delta[d]
// ---------------------------------------------------------------------------
__global__ __launch_bounds__(256) void scan_kernel(const float* __restrict__ Q,
                                                   const float* __restrict__ K,
                                                   const float* __restrict__ V,
                                                   const float* __restrict__ beta,
                                                   float* __restrict__ Y) {
    __shared__ float4 dbuf4[2][16];  // delta broadcast, double-buffered
    const int b = blockIdx.x >> 4;
    const int n = blockIdx.x & 15;
    const int t = threadIdx.x;
    const int r = t >> 2;  // 0..63 : row of M and MT this thread owns
    const int g = t & 3;   // 0..3  : 16-wide column slice

    float Mrow[16], MTrow[16];
#pragma unroll
    for (int j = 0; j < 16; ++j) { Mrow[j] = 0.f; MTrow[j] = 0.f; }

    int par = 0;
    for (int s = 0; s < SEQ; ++s) {
        const size_t base = ((size_t)(b * SEQ + s)) * D_MODEL + (size_t)n * HEAD_DIM;
        const float4* k4 = (const float4*)(K + base + g * 16);
        const float4* q4 = (const float4*)(Q + base + g * 16);
        float ks[16], qs[16];
#pragma unroll
        for (int j4 = 0; j4 < 4; ++j4) {
            float4 kv = k4[j4];
            float4 qv = q4[j4];
            ks[j4 * 4 + 0] = kv.x; ks[j4 * 4 + 1] = kv.y;
            ks[j4 * 4 + 2] = kv.z; ks[j4 * 4 + 3] = kv.w;
            qs[j4 * 4 + 0] = qv.x; qs[j4 * 4 + 1] = qv.y;
            qs[j4 * 4 + 2] = qv.z; qs[j4 * 4 + 3] = qv.w;
        }
        const float k_r = K[base + r];
        const float v_r = V[base + r];
        const float bta = beta[(size_t)(b * SEQ + s) * NHEAD + n];

        float outp = 0.f, retr = 0.f;
#pragma unroll
        for (int j = 0; j < 16; ++j) {
            outp += MTrow[j] * qs[j];
            retr += Mrow[j] * ks[j];
        }
        // reduce across the g-quad (lanes t^1, t^2) — all 4 lanes get the sum
        outp += __shfl_xor(outp, 1);
        outp += __shfl_xor(outp, 2);
        retr += __shfl_xor(retr, 1);
        retr += __shfl_xor(retr, 2);

        const float delta = v_r - retr;  // = delta[r]
        if (g == 0) {
            Y[base + r] = outp;                       // out_t[d=r], pre-update state
            ((float*)dbuf4[par])[r] = delta;          // broadcast delta vector
        }
        __syncthreads();

        const float bk = bta * k_r;    // beta * k[r]   (for M row update)
        const float bd = bta * delta;  // beta * delta[r] (for MT row update)
        float4 d0 = dbuf4[par][g * 4 + 0];
        float4 d1 = dbuf4[par][g * 4 + 1];
        float4 d2 = dbuf4[par][g * 4 + 2];
        float4 d3 = dbuf4[par][g * 4 + 3];
        float dl[16] = {d0.x, d0.y, d0.z, d0.w, d1.x, d1.y, d1.z, d1.w,
                        d2.x, d2.y, d2.z, d2.w, d3.x, d3.y, d3.z, d3.w};
#pragma unroll
        for (int j = 0; j < 16; ++j) {
            Mrow[j]  += bk * dl[j];   // M[r][16g+j] += beta*k[r]*delta[16g+j]
            MTrow[j] += bd * ks[j];   // MT[r][16g+j] += beta*k[16g+j]*delta[r]
        }
        par ^= 1;  // double buffer: one barrier per step is sufficient
    }
}

// ---------------------------------------------------------------------------
// RMSNorm in place over last dim (1024) + weight. One block (256 thr) per row.
// ---------------------------------------------------------------------------
__global__ __launch_bounds__(256) void rmsnorm_kernel(float* __restrict__ Y,
                                                      const float* __restrict__ w) {
    __shared__ float red[4];
    float* y = Y + (size_t)blockIdx.x * D_MODEL;
    const int t = threadIdx.x;
    const int wv = t >> 6, ln = t & 63;
    float4 v = ((float4*)y)[t];
    float ss = v.x * v.x + v.y * v.y + v.z * v.z + v.w * v.w;
#pragma unroll
    for (int off = 32; off; off >>= 1) ss += __shfl_xor(ss, off);
    if (ln == 0) red[wv] = ss;
    __syncthreads();
    float tot = red[0] + red[1] + red[2] + red[3];
    float inv = 1.f / sqrtf(tot * (1.f / D_MODEL) + 1e-6f);
    const float4 wv4 = ((const float4*)w)[t];
    v.x *= inv * wv4.x; v.y *= inv * wv4.y;
    v.z *= inv * wv4.z; v.w *= inv * wv4.w;
    ((float4*)y)[t] = v;
}

// ---------------------------------------------------------------------------
extern "C" void kernel_launch(void* const* d_in, const int* in_sizes, int n_in,
                              void* d_out, int out_size, void* d_ws, size_t ws_size,
                              hipStream_t stream) {
    const float* x     = (const float*)d_in[0];
    const float* Wq    = (const float*)d_in[1];
    const float* Wk    = (const float*)d_in[2];
    const float* Wv    = (const float*)d_in[3];
    const float* Wb    = (const float*)d_in[4];
    const float* Wo    = (const float*)d_in[5];
    const float* rms_w = (const float*)d_in[6];
    float* out = (float*)d_out;

    float* ws = (float*)d_ws;
    float* Q  = ws;                                   // 2048*1024
    float* Kp = Q + (size_t)ROWS * D_MODEL;           // 2048*1024
    float* Vp = Kp + (size_t)ROWS * D_MODEL;          // 2048*1024
    float* Y  = Vp + (size_t)ROWS * D_MODEL;          // 2048*1024
    float* Bt = Y + (size_t)ROWS * D_MODEL;           // 2048*16

    dim3 ggrid(D_MODEL / 64, ROWS / 64);  // (16, 32)
    gemm_bt<1><<<ggrid, 256, 0, stream>>>(x, Wq, Q, ROWS, D_MODEL, D_MODEL);
    gemm_bt<1><<<ggrid, 256, 0, stream>>>(x, Wk, Kp, ROWS, D_MODEL, D_MODEL);
    gemm_bt<1><<<ggrid, 256, 0, stream>>>(x, Wv, Vp, ROWS, D_MODEL, D_MODEL);
    beta_kernel<<<ROWS / 4, 256, 0, stream>>>(x, Wb, Bt);
    norm_qk<<<2 * ROWS * NHEAD / 4, 256, 0, stream>>>(Q, Kp);
    scan_kernel<<<BATCH * NHEAD, 256, 0, stream>>>(Q, Kp, Vp, Bt, Y);
    rmsnorm_kernel<<<ROWS, 256, 0, stream>>>(Y, rms_w);
    gemm_bt<0><<<ggrid, 256, 0, stream>>>(Y, Wo, out, ROWS, D_MODEL, D_MODEL);
}

// Round 2
// 897.409 us; speedup vs baseline: 1.5081x; 1.5081x over previous
//
#include <hip/hip_runtime.h>
#include <math.h>

#define D_MODEL 1024
#define NHEAD 16
#define HEAD_DIM 64
#define BATCH 2
#define SEQ 1024
#define ROWS (BATCH * SEQ)   // 2048
#define CHUNK 64
#define NCHUNK (SEQ / CHUNK) // 16

// ---------------------------------------------------------------------------
// async global->LDS helpers (gfx950). LDS dest = wave-uniform base + lane*size.
// ---------------------------------------------------------------------------
__device__ __forceinline__ void load_lds_16(const float* g, float* l) {
    __builtin_amdgcn_global_load_lds((const __attribute__((address_space(1))) void*)g,
                                     (__attribute__((address_space(3))) void*)l, 16, 0, 0);
}
__device__ __forceinline__ void load_lds_4(const float* g, float* l) {
    __builtin_amdgcn_global_load_lds((const __attribute__((address_space(1))) void*)g,
                                     (__attribute__((address_space(3))) void*)l, 4, 0, 0);
}
// LDS-only barrier: does NOT drain vmcnt, so async chunk prefetch stays in flight.
__device__ __forceinline__ void sync_lds() {
    asm volatile("s_waitcnt lgkmcnt(0)\n\ts_barrier" ::: "memory");
}

// ---------------------------------------------------------------------------
// GEMM: C[i][j] = act( sum_k A[i][k] * B[j][k] )   (unchanged from R1)
// ---------------------------------------------------------------------------
template <int ACT>
__global__ __launch_bounds__(256) void gemm_bt(const float* __restrict__ A,
                                               const float* __restrict__ B,
                                               float* __restrict__ C,
                                               int M, int N, int K) {
    __shared__ __align__(16) float As[16][68];
    __shared__ __align__(16) float Bs[16][68];

    const int tid = threadIdx.x;
    const int tx = tid & 15;
    const int ty = tid >> 4;
    const int row0 = blockIdx.y * 64;
    const int col0 = blockIdx.x * 64;
    const int lrow = tid >> 2;
    const int lk   = (tid & 3) * 4;

    float acc[4][4] = {};

    for (int k0 = 0; k0 < K; k0 += 16) {
        float4 av = *(const float4*)&A[(size_t)(row0 + lrow) * K + k0 + lk];
        float4 bv = *(const float4*)&B[(size_t)(col0 + lrow) * K + k0 + lk];
        As[lk + 0][lrow] = av.x; As[lk + 1][lrow] = av.y;
        As[lk + 2][lrow] = av.z; As[lk + 3][lrow] = av.w;
        Bs[lk + 0][lrow] = bv.x; Bs[lk + 1][lrow] = bv.y;
        Bs[lk + 2][lrow] = bv.z; Bs[lk + 3][lrow] = bv.w;
        __syncthreads();
#pragma unroll
        for (int kk = 0; kk < 16; ++kk) {
            float4 a = *(const float4*)&As[kk][ty * 4];
            float4 b = *(const float4*)&Bs[kk][tx * 4];
            float ar[4] = {a.x, a.y, a.z, a.w};
            float br[4] = {b.x, b.y, b.z, b.w};
#pragma unroll
            for (int i = 0; i < 4; ++i)
#pragma unroll
                for (int j = 0; j < 4; ++j) acc[i][j] += ar[i] * br[j];
        }
        __syncthreads();
    }

#pragma unroll
    for (int i = 0; i < 4; ++i) {
        float4 o;
        float v0 = acc[i][0], v1 = acc[i][1], v2 = acc[i][2], v3 = acc[i][3];
        if (ACT == 1) {
            v0 = v0 / (1.f + expf(-v0));
            v1 = v1 / (1.f + expf(-v1));
            v2 = v2 / (1.f + expf(-v2));
            v3 = v3 / (1.f + expf(-v3));
        }
        o.x = v0; o.y = v1; o.z = v2; o.w = v3;
        *(float4*)&C[(size_t)(row0 + ty * 4 + i) * N + col0 + tx * 4] = o;
    }
}

// ---------------------------------------------------------------------------
// beta = 2*sigmoid(x @ Wb^T)  : (ROWS, NHEAD). One wave per row.
// ---------------------------------------------------------------------------
__global__ __launch_bounds__(256) void beta_kernel(const float* __restrict__ x,
                                                   const float* __restrict__ Wb,
                                                   float* __restrict__ beta) {
    const int wave = blockIdx.x * 4 + (threadIdx.x >> 6);
    const int lane = threadIdx.x & 63;
    const float* xr = x + (size_t)wave * D_MODEL;
    float xv[16];
#pragma unroll
    for (int j = 0; j < 16; ++j) xv[j] = xr[lane + 64 * j];
    for (int n = 0; n < NHEAD; ++n) {
        const float* wr = Wb + (size_t)n * D_MODEL;
        float s = 0.f;
#pragma unroll
        for (int j = 0; j < 16; ++j) s += xv[j] * wr[lane + 64 * j];
#pragma unroll
        for (int off = 32; off; off >>= 1) s += __shfl_xor(s, off);
        if (lane == 0) beta[(size_t)wave * NHEAD + n] = 2.f / (1.f + expf(-s));
    }
}

// ---------------------------------------------------------------------------
// L2-normalize q and k per (row, head) over HEAD_DIM=64.
// ---------------------------------------------------------------------------
__global__ __launch_bounds__(256) void norm_qk(float* __restrict__ Q,
                                               float* __restrict__ Kp) {
    const int TOT = ROWS * NHEAD;
    int wave = blockIdx.x * 4 + (threadIdx.x >> 6);
    const int lane = threadIdx.x & 63;
    float* T = (wave < TOT) ? Q : Kp;
    int w = (wave < TOT) ? wave : wave - TOT;
    float* p = T + (size_t)(w >> 4) * D_MODEL + (size_t)(w & 15) * HEAD_DIM;
    float v = p[lane];
    float ss = v * v;
#pragma unroll
    for (int off = 32; off; off >>= 1) ss += __shfl_xor(ss, off);
    p[lane] = v / (sqrtf(ss) + 1e-6f);
}

// ---------------------------------------------------------------------------
// Sequential delta-rule scan, v2: LDS chunk staging (async, double-buffered)
// + lgkm-only per-step barrier + register ping-pong token prefetch.
// One block per (b, head). 256 threads: r = t>>2 (row 0..63), g = t&3.
// ---------------------------------------------------------------------------
struct Tok { float q[16]; float k[16]; float kr, vr, bt; };

__global__ __launch_bounds__(256, 1) void scan_kernel(const float* __restrict__ Q,
                                                      const float* __restrict__ K,
                                                      const float* __restrict__ V,
                                                      const float* __restrict__ Bt,
                                                      float* __restrict__ Y) {
    __shared__ __align__(16) float Lq[2][CHUNK][HEAD_DIM];
    __shared__ __align__(16) float Lk[2][CHUNK][HEAD_DIM];
    __shared__ __align__(16) float Lv[2][CHUNK][HEAD_DIM];
    __shared__ __align__(16) float Lb[2][CHUNK];
    __shared__ __align__(16) float Ldelta[2][HEAD_DIM];

    const int b = blockIdx.x >> 4;
    const int n = blockIdx.x & 15;
    const int t = threadIdx.x;
    const int r = t >> 2;           // row of M / MT owned
    const int g = t & 3;            // 16-wide column slice
    const int w = t >> 6;           // wave id (0..3)
    const int lane = t & 63;
    const int bS = b * SEQ;
    const int nOff = n * HEAD_DIM;

    float Mrow[16], MTrow[16];
#pragma unroll
    for (int j = 0; j < 16; ++j) { Mrow[j] = 0.f; MTrow[j] = 0.f; }

    int par = 0;

    // ---- async chunk loader: wave 0->Q, 1->K, 2->V, 3->beta ----
    auto issue_loads = [&](int c, int db) {
        const int s0 = c * CHUNK;
        if (w < 3) {
            const float* T = (w == 0) ? Q : (w == 1) ? K : V;
            float* dst = (w == 0) ? &Lq[db][0][0] : (w == 1) ? &Lk[db][0][0] : &Lv[db][0][0];
#pragma unroll
            for (int i = 0; i < 16; ++i) {
                int f = i * 64 + lane;
                int tok = f >> 4, f4 = f & 15;
                const float* gp = T + (size_t)(bS + s0 + tok) * D_MODEL + nOff + f4 * 4;
                load_lds_16(gp, dst + i * 256);  // wave writes 64 lanes x 16B contiguous
            }
        } else {
            const float* gp = Bt + (size_t)(bS + s0 + lane) * NHEAD + n;
            load_lds_4(gp, &Lb[db][0]);
        }
    };

    auto prefetch = [&](Tok& T, int bf, int s) {
#pragma unroll
        for (int j = 0; j < 4; ++j) {
            float4 qv = *(const float4*)&Lq[bf][s][g * 16 + 4 * j];
            float4 kv = *(const float4*)&Lk[bf][s][g * 16 + 4 * j];
            T.q[4 * j + 0] = qv.x; T.q[4 * j + 1] = qv.y;
            T.q[4 * j + 2] = qv.z; T.q[4 * j + 3] = qv.w;
            T.k[4 * j + 0] = kv.x; T.k[4 * j + 1] = kv.y;
            T.k[4 * j + 2] = kv.z; T.k[4 * j + 3] = kv.w;
        }
        T.kr = Lk[bf][s][r];
        T.vr = Lv[bf][s][r];
        T.bt = Lb[bf][s];
    };

    auto step = [&](int sAbs, Tok& cur, Tok& nxt, int pfIdx, int bf) {
        // dots against pre-update state (strictly causal)
        float o0 = 0.f, o1 = 0.f, r0 = 0.f, r1 = 0.f;
#pragma unroll
        for (int j = 0; j < 8; ++j) { o0 += MTrow[j] * cur.q[j]; r0 += Mrow[j] * cur.k[j]; }
#pragma unroll
        for (int j = 8; j < 16; ++j) { o1 += MTrow[j] * cur.q[j]; r1 += Mrow[j] * cur.k[j]; }
        float o = o0 + o1, rr = r0 + r1;
        o  += __shfl_xor(o, 1);  o  += __shfl_xor(o, 2);
        rr += __shfl_xor(rr, 1); rr += __shfl_xor(rr, 2);

        float delta = cur.vr - rr;
        if (g == 0) {
            Y[(size_t)(bS + sAbs) * D_MODEL + nOff + r] = o;   // out, pre-update
            Ldelta[par][r] = delta;
        }
        sync_lds();  // lgkm-only: async chunk loads stay in flight

        float dl[16];
#pragma unroll
        for (int j = 0; j < 4; ++j) {
            float4 dv = *(const float4*)&Ldelta[par][g * 16 + 4 * j];
            dl[4 * j + 0] = dv.x; dl[4 * j + 1] = dv.y;
            dl[4 * j + 2] = dv.z; dl[4 * j + 3] = dv.w;
        }
        if (pfIdx >= 0) prefetch(nxt, bf, pfIdx);   // overlap LDS latency w/ updates

        const float bk = cur.bt * cur.kr;   // beta * k[r]
        const float bd = cur.bt * delta;    // beta * delta[r]
#pragma unroll
        for (int j = 0; j < 16; ++j) {
            Mrow[j]  += bk * dl[j];     // M[r][16g+j]  += beta*k[r]*delta[16g+j]
            MTrow[j] += bd * cur.k[j];  // MT[r][16g+j] += beta*k[16g+j]*delta[r]
        }
        par ^= 1;
    };

    // prologue: chunk 0
    issue_loads(0, 0);
    __syncthreads();           // full drain: chunk 0 resident
    int buf = 0;
    Tok tA, tB;
    prefetch(tA, buf, 0);

    for (int c = 0; c < NCHUNK; ++c) {
        if (c < NCHUNK - 1) issue_loads(c + 1, buf ^ 1);
        const int s0 = c * CHUNK;
        for (int s = 0; s < CHUNK; s += 2) {
            step(s0 + s,     tA, tB, (s + 1 < CHUNK) ? s + 1 : -1, buf);
            step(s0 + s + 1, tB, tA, (s + 2 < CHUNK) ? s + 2 : -1, buf);
        }
        __syncthreads();       // full drain: next chunk resident, old buffer free
        if (c < NCHUNK - 1) {
            buf ^= 1;
            prefetch(tA, buf, 0);
        }
    }
}

// ---------------------------------------------------------------------------
// RMSNorm in place over last dim (1024) + weight. One block (256 thr) per row.
// ---------------------------------------------------------------------------
__global__ __launch_bounds__(256) void rmsnorm_kernel(float* __restrict__ Y,
                                                      const float* __restrict__ w) {
    __shared__ float red[4];
    float* y = Y + (size_t)blockIdx.x * D_MODEL;
    const int t = threadIdx.x;
    const int wv = t >> 6, ln = t & 63;
    float4 v = ((float4*)y)[t];
    float ss = v.x * v.x + v.y * v.y + v.z * v.z + v.w * v.w;
#pragma unroll
    for (int off = 32; off; off >>= 1) ss += __shfl_xor(ss, off);
    if (ln == 0) red[wv] = ss;
    __syncthreads();
    float tot = red[0] + red[1] + red[2] + red[3];
    float inv = 1.f / sqrtf(tot * (1.f / D_MODEL) + 1e-6f);
    const float4 wv4 = ((const float4*)w)[t];
    v.x *= inv * wv4.x; v.y *= inv * wv4.y;
    v.z *= inv * wv4.z; v.w *= inv * wv4.w;
    ((float4*)y)[t] = v;
}

// ---------------------------------------------------------------------------
extern "C" void kernel_launch(void* const* d_in, const int* in_sizes, int n_in,
                              void* d_out, int out_size, void* d_ws, size_t ws_size,
                              hipStream_t stream) {
    const float* x     = (const float*)d_in[0];
    const float* Wq    = (const float*)d_in[1];
    const float* Wk    = (const float*)d_in[2];
    const float* Wv    = (const float*)d_in[3];
    const float* Wb    = (const float*)d_in[4];
    const float* Wo    = (const float*)d_in[5];
    const float* rms_w = (const float*)d_in[6];
    float* out = (float*)d_out;

    float* ws = (float*)d_ws;
    float* Q  = ws;
    float* Kp = Q + (size_t)ROWS * D_MODEL;
    float* Vp = Kp + (size_t)ROWS * D_MODEL;
    float* Y  = Vp + (size_t)ROWS * D_MODEL;
    float* Bt = Y + (size_t)ROWS * D_MODEL;

    dim3 ggrid(D_MODEL / 64, ROWS / 64);
    gemm_bt<1><<<ggrid, 256, 0, stream>>>(x, Wq, Q, ROWS, D_MODEL, D_MODEL);
    gemm_bt<1><<<ggrid, 256, 0, stream>>>(x, Wk, Kp, ROWS, D_MODEL, D_MODEL);
    gemm_bt<1><<<ggrid, 256, 0, stream>>>(x, Wv, Vp, ROWS, D_MODEL, D_MODEL);
    beta_kernel<<<ROWS / 4, 256, 0, stream>>>(x, Wb, Bt);
    norm_qk<<<2 * ROWS * NHEAD / 4, 256, 0, stream>>>(Q, Kp);
    scan_kernel<<<BATCH * NHEAD, 256, 0, stream>>>(Q, Kp, Vp, Bt, Y);
    rmsnorm_kernel<<<ROWS, 256, 0, stream>>>(Y, rms_w);
    gemm_bt<0><<<ggrid, 256, 0, stream>>>(Y, Wo, out, ROWS, D_MODEL, D_MODEL);
}

// Round 3
// 874.779 us; speedup vs baseline: 1.5471x; 1.0259x over previous
//
#include <hip/hip_runtime.h>
#include <math.h>

#define D_MODEL 1024
#define NHEAD 16
#define HEAD_DIM 64
#define BATCH 2
#define SEQ 1024
#define ROWS (BATCH * SEQ)   // 2048
#define CHUNK 64
#define NCHUNK (SEQ / CHUNK) // 16

typedef __attribute__((ext_vector_type(8))) short bf16x8;
typedef __attribute__((ext_vector_type(8))) unsigned short ushort8;
typedef __attribute__((ext_vector_type(4))) float f32x4;

// ---------------------------------------------------------------------------
// async global->LDS helpers (gfx950). LDS dest = wave-uniform base + lane*size.
// ---------------------------------------------------------------------------
__device__ __forceinline__ void load_lds_16(const float* g, float* l) {
    __builtin_amdgcn_global_load_lds((const __attribute__((address_space(1))) void*)g,
                                     (__attribute__((address_space(3))) void*)l, 16, 0, 0);
}
__device__ __forceinline__ void load_lds_4(const float* g, float* l) {
    __builtin_amdgcn_global_load_lds((const __attribute__((address_space(1))) void*)g,
                                     (__attribute__((address_space(3))) void*)l, 4, 0, 0);
}
// LDS-only barrier: does NOT drain vmcnt, so async chunk prefetch stays in flight.
__device__ __forceinline__ void sync_lds() {
    asm volatile("s_waitcnt lgkmcnt(0)\n\ts_barrier" ::: "memory");
}

// fp32 -> bf16 RNE + residual
__device__ __forceinline__ unsigned short f2bf(float x) {
    unsigned int u = __float_as_uint(x);
    unsigned int r = (u + 0x7FFFu + ((u >> 16) & 1u)) >> 16;
    return (unsigned short)r;
}
__device__ __forceinline__ float bf2f(unsigned short h) {
    return __uint_as_float(((unsigned int)h) << 16);
}

// ---------------------------------------------------------------------------
// Split-bf16 MFMA GEMM: C[i][j] = act( sum_k A[i][k] * B[j][k] )
// A: (M x K) rm, B: (N x K) rm, C: (M x N) rm. fp32 in/out.
// Each fp32 split a = hi + lo (bf16 each); product uses hi*hi + hi*lo + lo*hi
// (drops lo*lo ~ 2^-16 rel) -> fp32-quality result at 3x bf16-MFMA cost.
// Tile 128x128, BK=32, 256 thr = 4 waves in 2x2; each wave 64x64 = 4x4 mfma
// 16x16x32 tiles. ACT: 0 = identity, 1 = silu.
// ---------------------------------------------------------------------------
#define LDST 40  // LDS row stride in bf16 elems (32 + 8 pad; 80B, 16B-aligned)

template <int ACT>
__global__ __launch_bounds__(256) void gemm_mfma(const float* __restrict__ A,
                                                 const float* __restrict__ B,
                                                 float* __restrict__ C,
                                                 int M, int N, int K) {
    __shared__ unsigned short Ahi[128 * LDST], Alo[128 * LDST];
    __shared__ unsigned short Bhi[128 * LDST], Blo[128 * LDST];

    const int t = threadIdx.x;
    const int wave = t >> 6, lane = t & 63;
    const int wm = wave >> 1, wn = wave & 1;     // 2x2 wave grid
    const int row0 = blockIdx.y * 128, col0 = blockIdx.x * 128;
    const int sr = t >> 1;                        // staging row 0..127
    const int sh = t & 1;                         // staging k-half (16 elems)
    const int m16 = lane & 15, kg = lane >> 4;    // mfma fragment ids

    f32x4 acc[4][4];
#pragma unroll
    for (int i = 0; i < 4; ++i)
#pragma unroll
        for (int j = 0; j < 4; ++j) acc[i][j] = (f32x4){0.f, 0.f, 0.f, 0.f};

    const float* ga = A + (size_t)(row0 + sr) * K + sh * 16;
    const float* gb = B + (size_t)(col0 + sr) * K + sh * 16;
    const int sbase = sr * LDST + sh * 16;

    for (int k0 = 0; k0 < K; k0 += 32) {
        // ---- stage: fp32 load, split to (hi,lo) bf16, write LDS ----
        float af[16], bf[16];
#pragma unroll
        for (int i = 0; i < 4; ++i) {
            float4 a4 = *(const float4*)(ga + k0 + i * 4);
            float4 b4 = *(const float4*)(gb + k0 + i * 4);
            af[i * 4 + 0] = a4.x; af[i * 4 + 1] = a4.y; af[i * 4 + 2] = a4.z; af[i * 4 + 3] = a4.w;
            bf[i * 4 + 0] = b4.x; bf[i * 4 + 1] = b4.y; bf[i * 4 + 2] = b4.z; bf[i * 4 + 3] = b4.w;
        }
        ushort8 ah0, ah1, al0, al1, bh0, bh1, bl0, bl1;
#pragma unroll
        for (int j = 0; j < 8; ++j) {
            unsigned short h = f2bf(af[j]);       ah0[j] = h;
            al0[j] = f2bf(af[j] - bf2f(h));
            h = f2bf(af[j + 8]);                  ah1[j] = h;
            al1[j] = f2bf(af[j + 8] - bf2f(h));
            h = f2bf(bf[j]);                      bh0[j] = h;
            bl0[j] = f2bf(bf[j] - bf2f(h));
            h = f2bf(bf[j + 8]);                  bh1[j] = h;
            bl1[j] = f2bf(bf[j + 8] - bf2f(h));
        }
        *(ushort8*)&Ahi[sbase]     = ah0;  *(ushort8*)&Ahi[sbase + 8] = ah1;
        *(ushort8*)&Alo[sbase]     = al0;  *(ushort8*)&Alo[sbase + 8] = al1;
        *(ushort8*)&Bhi[sbase]     = bh0;  *(ushort8*)&Bhi[sbase + 8] = bh1;
        *(ushort8*)&Blo[sbase]     = bl0;  *(ushort8*)&Blo[sbase + 8] = bl1;
        __syncthreads();

        // ---- fragments: A[m=lane&15][k=kg*8+j] ; B-tile rows are C-cols ----
        bf16x8 fah[4], fal[4], fbh[4], fbl[4];
#pragma unroll
        for (int i = 0; i < 4; ++i) {
            const int ar = (wm * 64 + i * 16 + m16) * LDST + kg * 8;
            const int br = (wn * 64 + i * 16 + m16) * LDST + kg * 8;
            fah[i] = *(const bf16x8*)&Ahi[ar];
            fal[i] = *(const bf16x8*)&Alo[ar];
            fbh[i] = *(const bf16x8*)&Bhi[br];
            fbl[i] = *(const bf16x8*)&Blo[br];
        }
#pragma unroll
        for (int i = 0; i < 4; ++i)
#pragma unroll
            for (int j = 0; j < 4; ++j) {
                acc[i][j] = __builtin_amdgcn_mfma_f32_16x16x32_bf16(fal[i], fbh[j], acc[i][j], 0, 0, 0);
                acc[i][j] = __builtin_amdgcn_mfma_f32_16x16x32_bf16(fah[i], fbl[j], acc[i][j], 0, 0, 0);
                acc[i][j] = __builtin_amdgcn_mfma_f32_16x16x32_bf16(fah[i], fbh[j], acc[i][j], 0, 0, 0);
            }
        __syncthreads();
    }

    // ---- epilogue: C/D layout col=lane&15, row=kg*4+reg ----
#pragma unroll
    for (int i = 0; i < 4; ++i) {
#pragma unroll
        for (int j = 0; j < 4; ++j) {
            const int col = col0 + wn * 64 + j * 16 + m16;
            const int rowb = row0 + wm * 64 + i * 16 + kg * 4;
#pragma unroll
            for (int rg = 0; rg < 4; ++rg) {
                float v = acc[i][j][rg];
                if (ACT == 1) v = v / (1.f + expf(-v));
                C[(size_t)(rowb + rg) * N + col] = v;
            }
        }
    }
}

// ---------------------------------------------------------------------------
// beta = 2*sigmoid(x @ Wb^T)  : (ROWS, NHEAD). One wave per row.
// ---------------------------------------------------------------------------
__global__ __launch_bounds__(256) void beta_kernel(const float* __restrict__ x,
                                                   const float* __restrict__ Wb,
                                                   float* __restrict__ beta) {
    const int wave = blockIdx.x * 4 + (threadIdx.x >> 6);
    const int lane = threadIdx.x & 63;
    const float* xr = x + (size_t)wave * D_MODEL;
    float xv[16];
#pragma unroll
    for (int j = 0; j < 16; ++j) xv[j] = xr[lane + 64 * j];
    for (int n = 0; n < NHEAD; ++n) {
        const float* wr = Wb + (size_t)n * D_MODEL;
        float s = 0.f;
#pragma unroll
        for (int j = 0; j < 16; ++j) s += xv[j] * wr[lane + 64 * j];
#pragma unroll
        for (int off = 32; off; off >>= 1) s += __shfl_xor(s, off);
        if (lane == 0) beta[(size_t)wave * NHEAD + n] = 2.f / (1.f + expf(-s));
    }
}

// ---------------------------------------------------------------------------
// L2-normalize q and k per (row, head) over HEAD_DIM=64.
// ---------------------------------------------------------------------------
__global__ __launch_bounds__(256) void norm_qk(float* __restrict__ Q,
                                               float* __restrict__ Kp) {
    const int TOT = ROWS * NHEAD;
    int wave = blockIdx.x * 4 + (threadIdx.x >> 6);
    const int lane = threadIdx.x & 63;
    float* T = (wave < TOT) ? Q : Kp;
    int w = (wave < TOT) ? wave : wave - TOT;
    float* p = T + (size_t)(w >> 4) * D_MODEL + (size_t)(w & 15) * HEAD_DIM;
    float v = p[lane];
    float ss = v * v;
#pragma unroll
    for (int off = 32; off; off >>= 1) ss += __shfl_xor(ss, off);
    p[lane] = v / (sqrtf(ss) + 1e-6f);
}

// ---------------------------------------------------------------------------
// Sequential delta-rule scan (unchanged from R2): LDS chunk staging (async,
// double-buffered) + lgkm-only per-step barrier + register token prefetch.
// One block per (b, head). 256 threads: r = t>>2 (row 0..63), g = t&3.
// ---------------------------------------------------------------------------
struct Tok { float q[16]; float k[16]; float kr, vr, bt; };

__global__ __launch_bounds__(256, 1) void scan_kernel(const float* __restrict__ Q,
                                                      const float* __restrict__ K,
                                                      const float* __restrict__ V,
                                                      const float* __restrict__ Bt,
                                                      float* __restrict__ Y) {
    __shared__ __align__(16) float Lq[2][CHUNK][HEAD_DIM];
    __shared__ __align__(16) float Lk[2][CHUNK][HEAD_DIM];
    __shared__ __align__(16) float Lv[2][CHUNK][HEAD_DIM];
    __shared__ __align__(16) float Lb[2][CHUNK];
    __shared__ __align__(16) float Ldelta[2][HEAD_DIM];

    const int b = blockIdx.x >> 4;
    const int n = blockIdx.x & 15;
    const int t = threadIdx.x;
    const int r = t >> 2;
    const int g = t & 3;
    const int w = t >> 6;
    const int lane = t & 63;
    const int bS = b * SEQ;
    const int nOff = n * HEAD_DIM;

    float Mrow[16], MTrow[16];
#pragma unroll
    for (int j = 0; j < 16; ++j) { Mrow[j] = 0.f; MTrow[j] = 0.f; }

    int par = 0;

    auto issue_loads = [&](int c, int db) {
        const int s0 = c * CHUNK;
        if (w < 3) {
            const float* T = (w == 0) ? Q : (w == 1) ? K : V;
            float* dst = (w == 0) ? &Lq[db][0][0] : (w == 1) ? &Lk[db][0][0] : &Lv[db][0][0];
#pragma unroll
            for (int i = 0; i < 16; ++i) {
                int f = i * 64 + lane;
                int tok = f >> 4, f4 = f & 15;
                const float* gp = T + (size_t)(bS + s0 + tok) * D_MODEL + nOff + f4 * 4;
                load_lds_16(gp, dst + i * 256);
            }
        } else {
            const float* gp = Bt + (size_t)(bS + s0 + lane) * NHEAD + n;
            load_lds_4(gp, &Lb[db][0]);
        }
    };

    auto prefetch = [&](Tok& T, int bf, int s) {
#pragma unroll
        for (int j = 0; j < 4; ++j) {
            float4 qv = *(const float4*)&Lq[bf][s][g * 16 + 4 * j];
            float4 kv = *(const float4*)&Lk[bf][s][g * 16 + 4 * j];
            T.q[4 * j + 0] = qv.x; T.q[4 * j + 1] = qv.y;
            T.q[4 * j + 2] = qv.z; T.q[4 * j + 3] = qv.w;
            T.k[4 * j + 0] = kv.x; T.k[4 * j + 1] = kv.y;
            T.k[4 * j + 2] = kv.z; T.k[4 * j + 3] = kv.w;
        }
        T.kr = Lk[bf][s][r];
        T.vr = Lv[bf][s][r];
        T.bt = Lb[bf][s];
    };

    auto step = [&](int sAbs, Tok& cur, Tok& nxt, int pfIdx, int bf) {
        float o0 = 0.f, o1 = 0.f, r0 = 0.f, r1 = 0.f;
#pragma unroll
        for (int j = 0; j < 8; ++j) { o0 += MTrow[j] * cur.q[j]; r0 += Mrow[j] * cur.k[j]; }
#pragma unroll
        for (int j = 8; j < 16; ++j) { o1 += MTrow[j] * cur.q[j]; r1 += Mrow[j] * cur.k[j]; }
        float o = o0 + o1, rr = r0 + r1;
        o  += __shfl_xor(o, 1);  o  += __shfl_xor(o, 2);
        rr += __shfl_xor(rr, 1); rr += __shfl_xor(rr, 2);

        float delta = cur.vr - rr;
        if (g == 0) {
            Y[(size_t)(bS + sAbs) * D_MODEL + nOff + r] = o;
            Ldelta[par][r] = delta;
        }
        sync_lds();

        float dl[16];
#pragma unroll
        for (int j = 0; j < 4; ++j) {
            float4 dv = *(const float4*)&Ldelta[par][g * 16 + 4 * j];
            dl[4 * j + 0] = dv.x; dl[4 * j + 1] = dv.y;
            dl[4 * j + 2] = dv.z; dl[4 * j + 3] = dv.w;
        }
        if (pfIdx >= 0) prefetch(nxt, bf, pfIdx);

        const float bk = cur.bt * cur.kr;
        const float bd = cur.bt * delta;
#pragma unroll
        for (int j = 0; j < 16; ++j) {
            Mrow[j]  += bk * dl[j];
            MTrow[j] += bd * cur.k[j];
        }
        par ^= 1;
    };

    issue_loads(0, 0);
    __syncthreads();
    int buf = 0;
    Tok tA, tB;
    prefetch(tA, buf, 0);

    for (int c = 0; c < NCHUNK; ++c) {
        if (c < NCHUNK - 1) issue_loads(c + 1, buf ^ 1);
        const int s0 = c * CHUNK;
        for (int s = 0; s < CHUNK; s += 2) {
            step(s0 + s,     tA, tB, (s + 1 < CHUNK) ? s + 1 : -1, buf);
            step(s0 + s + 1, tB, tA, (s + 2 < CHUNK) ? s + 2 : -1, buf);
        }
        __syncthreads();
        if (c < NCHUNK - 1) {
            buf ^= 1;
            prefetch(tA, buf, 0);
        }
    }
}

// ---------------------------------------------------------------------------
// RMSNorm in place over last dim (1024) + weight. One block (256 thr) per row.
// ---------------------------------------------------------------------------
__global__ __launch_bounds__(256) void rmsnorm_kernel(float* __restrict__ Y,
                                                      const float* __restrict__ w) {
    __shared__ float red[4];
    float* y = Y + (size_t)blockIdx.x * D_MODEL;
    const int t = threadIdx.x;
    const int wv = t >> 6, ln = t & 63;
    float4 v = ((float4*)y)[t];
    float ss = v.x * v.x + v.y * v.y + v.z * v.z + v.w * v.w;
#pragma unroll
    for (int off = 32; off; off >>= 1) ss += __shfl_xor(ss, off);
    if (ln == 0) red[wv] = ss;
    __syncthreads();
    float tot = red[0] + red[1] + red[2] + red[3];
    float inv = 1.f / sqrtf(tot * (1.f / D_MODEL) + 1e-6f);
    const float4 wv4 = ((const float4*)w)[t];
    v.x *= inv * wv4.x; v.y *= inv * wv4.y;
    v.z *= inv * wv4.z; v.w *= inv * wv4.w;
    ((float4*)y)[t] = v;
}

// ---------------------------------------------------------------------------
extern "C" void kernel_launch(void* const* d_in, const int* in_sizes, int n_in,
                              void* d_out, int out_size, void* d_ws, size_t ws_size,
                              hipStream_t stream) {
    const float* x     = (const float*)d_in[0];
    const float* Wq    = (const float*)d_in[1];
    const float* Wk    = (const float*)d_in[2];
    const float* Wv    = (const float*)d_in[3];
    const float* Wb    = (const float*)d_in[4];
    const float* Wo    = (const float*)d_in[5];
    const float* rms_w = (const float*)d_in[6];
    float* out = (float*)d_out;

    float* ws = (float*)d_ws;
    float* Q  = ws;
    float* Kp = Q + (size_t)ROWS * D_MODEL;
    float* Vp = Kp + (size_t)ROWS * D_MODEL;
    float* Y  = Vp + (size_t)ROWS * D_MODEL;
    float* Bt = Y + (size_t)ROWS * D_MODEL;

    dim3 ggrid(D_MODEL / 128, ROWS / 128);  // (8, 16)
    gemm_mfma<1><<<ggrid, 256, 0, stream>>>(x, Wq, Q, ROWS, D_MODEL, D_MODEL);
    gemm_mfma<1><<<ggrid, 256, 0, stream>>>(x, Wk, Kp, ROWS, D_MODEL, D_MODEL);
    gemm_mfma<1><<<ggrid, 256, 0, stream>>>(x, Wv, Vp, ROWS, D_MODEL, D_MODEL);
    beta_kernel<<<ROWS / 4, 256, 0, stream>>>(x, Wb, Bt);
    norm_qk<<<2 * ROWS * NHEAD / 4, 256, 0, stream>>>(Q, Kp);
    scan_kernel<<<BATCH * NHEAD, 256, 0, stream>>>(Q, Kp, Vp, Bt, Y);
    rmsnorm_kernel<<<ROWS, 256, 0, stream>>>(Y, rms_w);
    gemm_mfma<0><<<ggrid, 256, 0, stream>>>(Y, Wo, out, ROWS, D_MODEL, D_MODEL);
}

// Round 4
// 777.982 us; speedup vs baseline: 1.7396x; 1.1244x over previous
//
#include <hip/hip_runtime.h>
#include <math.h>

#define D_MODEL 1024
#define NHEAD 16
#define HEAD_DIM 64
#define BATCH 2
#define SEQ 1024
#define ROWS (BATCH * SEQ)        // 2048
#define RD (ROWS * D_MODEL)       // 2097152
#define WSZ (D_MODEL * D_MODEL)   // 1048576
#define CHUNK 64
#define NCHUNK (SEQ / CHUNK)      // 16

typedef __attribute__((ext_vector_type(8))) short bf16x8;
typedef __attribute__((ext_vector_type(8))) unsigned short ushort8;
typedef __attribute__((ext_vector_type(4))) unsigned short us4;
typedef __attribute__((ext_vector_type(4))) float f32x4;

// ---------------------------------------------------------------------------
// helpers
// ---------------------------------------------------------------------------
__device__ __forceinline__ void load_lds_16f(const float* g, float* l) {
    __builtin_amdgcn_global_load_lds((const __attribute__((address_space(1))) void*)g,
                                     (__attribute__((address_space(3))) void*)l, 16, 0, 0);
}
__device__ __forceinline__ void load_lds_4f(const float* g, float* l) {
    __builtin_amdgcn_global_load_lds((const __attribute__((address_space(1))) void*)g,
                                     (__attribute__((address_space(3))) void*)l, 4, 0, 0);
}
__device__ __forceinline__ void load_lds_16u(const unsigned short* g, unsigned short* l) {
    __builtin_amdgcn_global_load_lds((const __attribute__((address_space(1))) void*)g,
                                     (__attribute__((address_space(3))) void*)l, 16, 0, 0);
}
// LDS-only barrier: does NOT drain vmcnt (async chunk prefetch stays in flight).
__device__ __forceinline__ void sync_lds() {
    asm volatile("s_waitcnt lgkmcnt(0)\n\ts_barrier" ::: "memory");
}
// fp32 -> bf16 RNE, and back
__device__ __forceinline__ unsigned short f2bf(float x) {
    unsigned int u = __float_as_uint(x);
    unsigned int r = (u + 0x7FFFu + ((u >> 16) & 1u)) >> 16;
    return (unsigned short)r;
}
__device__ __forceinline__ float bf2f(unsigned short h) {
    return __uint_as_float(((unsigned int)h) << 16);
}
// quad sum via DPP (lanes t^1, t^2) — VALU pipe, no LDS latency.
// quad_perm[1,0,3,2] = 0xB1 (xor1); quad_perm[2,3,0,1] = 0x4E (xor2).
__device__ __forceinline__ float quad_add(float x) {
    float y = __int_as_float(__builtin_amdgcn_update_dpp(0, __float_as_int(x), 0xB1, 0xF, 0xF, true));
    x += y;
    y = __int_as_float(__builtin_amdgcn_update_dpp(0, __float_as_int(x), 0x4E, 0xF, 0xF, true));
    return x + y;
}

// ---------------------------------------------------------------------------
// split: fp32 -> (hi, lo) bf16 buffers. n4 = n/4 float4 groups.
// ---------------------------------------------------------------------------
__global__ __launch_bounds__(256) void split_kernel(const float* __restrict__ X,
                                                    unsigned short* __restrict__ H,
                                                    unsigned short* __restrict__ L,
                                                    int n4) {
    int i = blockIdx.x * 256 + threadIdx.x;
    if (i >= n4) return;
    float4 v = ((const float4*)X)[i];
    us4 h, l;
    h.x = f2bf(v.x); l.x = f2bf(v.x - bf2f(h.x));
    h.y = f2bf(v.y); l.y = f2bf(v.y - bf2f(h.y));
    h.z = f2bf(v.z); l.z = f2bf(v.z - bf2f(h.z));
    h.w = f2bf(v.w); l.w = f2bf(v.w - bf2f(h.w));
    ((us4*)H)[i] = h;
    ((us4*)L)[i] = l;
}

// ---------------------------------------------------------------------------
// Fast GEMM on pre-split inputs: C = act(A · B^T), A:(M,K) B:(N,K) fp32-split.
// Tile 128(M)x64(N), BK=32, 256 thr = 4 waves (2x2; wave tile 64x32).
// LDS in fragment order: sub-tile (16 rows x 32 k) = 512 bf16, element
// (kg*16+m16)*8+j holds X[row=m16][k=kg*8+j] — matches both the wave-uniform
// global_load_lds lane layout AND the mfma fragment ds_read_b128 (conflict-free).
// ---------------------------------------------------------------------------
template <int ACT>
__global__ __launch_bounds__(256) void gemm_bf16s(const unsigned short* __restrict__ Ah,
                                                  const unsigned short* __restrict__ Al,
                                                  const unsigned short* __restrict__ Bh,
                                                  const unsigned short* __restrict__ Bl,
                                                  float* __restrict__ C,
                                                  int M, int N, int K) {
    __shared__ unsigned short LA[2][8 * 512];   // [hi/lo][8 sub-tiles]
    __shared__ unsigned short LB[2][4 * 512];   // [hi/lo][4 sub-tiles]

    const int t = threadIdx.x;
    const int wave = t >> 6, lane = t & 63;
    const int wm = wave >> 1, wn = wave & 1;
    const int m16 = lane & 15, kg = lane >> 4;
    const int row0 = blockIdx.y * 128, col0 = blockIdx.x * 64;

    f32x4 acc[4][2];
#pragma unroll
    for (int i = 0; i < 4; ++i)
#pragma unroll
        for (int j = 0; j < 2; ++j) acc[i][j] = (f32x4){0.f, 0.f, 0.f, 0.f};

    for (int k0 = 0; k0 < K; k0 += 32) {
        // ---- stage: 24 chunks of 1KB (one sub-tile each); wave w does 6 ----
#pragma unroll
        for (int ci = 0; ci < 6; ++ci) {
            const int c = wave * 6 + ci;
            const unsigned short* src;
            unsigned short* dst;
            int g16, rbase;
            if (c < 8)       { src = Ah; dst = &LA[0][c * 512];        g16 = c;      rbase = row0; }
            else if (c < 16) { src = Al; dst = &LA[1][(c - 8) * 512];  g16 = c - 8;  rbase = row0; }
            else if (c < 20) { src = Bh; dst = &LB[0][(c - 16) * 512]; g16 = c - 16; rbase = col0; }
            else             { src = Bl; dst = &LB[1][(c - 20) * 512]; g16 = c - 20; rbase = col0; }
            const unsigned short* gp = src + (size_t)(rbase + g16 * 16 + m16) * K + k0 + kg * 8;
            load_lds_16u(gp, dst);
        }
        __syncthreads();   // drains vmcnt: staged data visible

        bf16x8 fah[4], fal[4], fbh[2], fbl[2];
#pragma unroll
        for (int mt = 0; mt < 4; ++mt) {
            const int off = (wm * 4 + mt) * 512 + lane * 8;
            fah[mt] = *(const bf16x8*)&LA[0][off];
            fal[mt] = *(const bf16x8*)&LA[1][off];
        }
#pragma unroll
        for (int nt = 0; nt < 2; ++nt) {
            const int off = (wn * 2 + nt) * 512 + lane * 8;
            fbh[nt] = *(const bf16x8*)&LB[0][off];
            fbl[nt] = *(const bf16x8*)&LB[1][off];
        }
#pragma unroll
        for (int mt = 0; mt < 4; ++mt)
#pragma unroll
            for (int nt = 0; nt < 2; ++nt) {
                acc[mt][nt] = __builtin_amdgcn_mfma_f32_16x16x32_bf16(fal[mt], fbh[nt], acc[mt][nt], 0, 0, 0);
                acc[mt][nt] = __builtin_amdgcn_mfma_f32_16x16x32_bf16(fah[mt], fbl[nt], acc[mt][nt], 0, 0, 0);
                acc[mt][nt] = __builtin_amdgcn_mfma_f32_16x16x32_bf16(fah[mt], fbh[nt], acc[mt][nt], 0, 0, 0);
            }
        __syncthreads();   // frags consumed: safe to overwrite LDS
    }

    // epilogue: C/D layout col=lane&15, row=(lane>>4)*4+reg  (R3-validated)
#pragma unroll
    for (int mt = 0; mt < 4; ++mt)
#pragma unroll
        for (int nt = 0; nt < 2; ++nt) {
            const int rowb = row0 + wm * 64 + mt * 16 + kg * 4;
            const int col  = col0 + wn * 32 + nt * 16 + m16;
#pragma unroll
            for (int rg = 0; rg < 4; ++rg) {
                float v = acc[mt][nt][rg];
                if (ACT == 1) v = v / (1.f + expf(-v));
                C[(size_t)(rowb + rg) * N + col] = v;
            }
        }
}

// ---------------------------------------------------------------------------
// Fallback GEMM (R3, inline split) — used only if ws_size is too small.
// ---------------------------------------------------------------------------
#define LDST 40
template <int ACT>
__global__ __launch_bounds__(256) void gemm_mfma(const float* __restrict__ A,
                                                 const float* __restrict__ B,
                                                 float* __restrict__ C,
                                                 int M, int N, int K) {
    __shared__ unsigned short Ahi[128 * LDST], Alo[128 * LDST];
    __shared__ unsigned short Bhi[128 * LDST], Blo[128 * LDST];

    const int t = threadIdx.x;
    const int wave = t >> 6, lane = t & 63;
    const int wm = wave >> 1, wn = wave & 1;
    const int row0 = blockIdx.y * 128, col0 = blockIdx.x * 128;
    const int sr = t >> 1;
    const int sh = t & 1;
    const int m16 = lane & 15, kg = lane >> 4;

    f32x4 acc[4][4];
#pragma unroll
    for (int i = 0; i < 4; ++i)
#pragma unroll
        for (int j = 0; j < 4; ++j) acc[i][j] = (f32x4){0.f, 0.f, 0.f, 0.f};

    const float* ga = A + (size_t)(row0 + sr) * K + sh * 16;
    const float* gb = B + (size_t)(col0 + sr) * K + sh * 16;
    const int sbase = sr * LDST + sh * 16;

    for (int k0 = 0; k0 < K; k0 += 32) {
        float af[16], bf[16];
#pragma unroll
        for (int i = 0; i < 4; ++i) {
            float4 a4 = *(const float4*)(ga + k0 + i * 4);
            float4 b4 = *(const float4*)(gb + k0 + i * 4);
            af[i * 4 + 0] = a4.x; af[i * 4 + 1] = a4.y; af[i * 4 + 2] = a4.z; af[i * 4 + 3] = a4.w;
            bf[i * 4 + 0] = b4.x; bf[i * 4 + 1] = b4.y; bf[i * 4 + 2] = b4.z; bf[i * 4 + 3] = b4.w;
        }
        ushort8 ah0, ah1, al0, al1, bh0, bh1, bl0, bl1;
#pragma unroll
        for (int j = 0; j < 8; ++j) {
            unsigned short h = f2bf(af[j]);       ah0[j] = h; al0[j] = f2bf(af[j] - bf2f(h));
            h = f2bf(af[j + 8]);                  ah1[j] = h; al1[j] = f2bf(af[j + 8] - bf2f(h));
            h = f2bf(bf[j]);                      bh0[j] = h; bl0[j] = f2bf(bf[j] - bf2f(h));
            h = f2bf(bf[j + 8]);                  bh1[j] = h; bl1[j] = f2bf(bf[j + 8] - bf2f(h));
        }
        *(ushort8*)&Ahi[sbase] = ah0;  *(ushort8*)&Ahi[sbase + 8] = ah1;
        *(ushort8*)&Alo[sbase] = al0;  *(ushort8*)&Alo[sbase + 8] = al1;
        *(ushort8*)&Bhi[sbase] = bh0;  *(ushort8*)&Bhi[sbase + 8] = bh1;
        *(ushort8*)&Blo[sbase] = bl0;  *(ushort8*)&Blo[sbase + 8] = bl1;
        __syncthreads();

        bf16x8 fah[4], fal[4], fbh[4], fbl[4];
#pragma unroll
        for (int i = 0; i < 4; ++i) {
            const int ar = (wm * 64 + i * 16 + m16) * LDST + kg * 8;
            const int br = (wn * 64 + i * 16 + m16) * LDST + kg * 8;
            fah[i] = *(const bf16x8*)&Ahi[ar];
            fal[i] = *(const bf16x8*)&Alo[ar];
            fbh[i] = *(const bf16x8*)&Bhi[br];
            fbl[i] = *(const bf16x8*)&Blo[br];
        }
#pragma unroll
        for (int i = 0; i < 4; ++i)
#pragma unroll
            for (int j = 0; j < 4; ++j) {
                acc[i][j] = __builtin_amdgcn_mfma_f32_16x16x32_bf16(fal[i], fbh[j], acc[i][j], 0, 0, 0);
                acc[i][j] = __builtin_amdgcn_mfma_f32_16x16x32_bf16(fah[i], fbl[j], acc[i][j], 0, 0, 0);
                acc[i][j] = __builtin_amdgcn_mfma_f32_16x16x32_bf16(fah[i], fbh[j], acc[i][j], 0, 0, 0);
            }
        __syncthreads();
    }

#pragma unroll
    for (int i = 0; i < 4; ++i)
#pragma unroll
        for (int j = 0; j < 4; ++j) {
            const int col = col0 + wn * 64 + j * 16 + m16;
            const int rowb = row0 + wm * 64 + i * 16 + kg * 4;
#pragma unroll
            for (int rg = 0; rg < 4; ++rg) {
                float v = acc[i][j][rg];
                if (ACT == 1) v = v / (1.f + expf(-v));
                C[(size_t)(rowb + rg) * N + col] = v;
            }
        }
}

// ---------------------------------------------------------------------------
// beta = 2*sigmoid(x @ Wb^T)  : (ROWS, NHEAD). One wave per row.
// ---------------------------------------------------------------------------
__global__ __launch_bounds__(256) void beta_kernel(const float* __restrict__ x,
                                                   const float* __restrict__ Wb,
                                                   float* __restrict__ beta) {
    const int wave = blockIdx.x * 4 + (threadIdx.x >> 6);
    const int lane = threadIdx.x & 63;
    const float* xr = x + (size_t)wave * D_MODEL;
    float xv[16];
#pragma unroll
    for (int j = 0; j < 16; ++j) xv[j] = xr[lane + 64 * j];
    for (int n = 0; n < NHEAD; ++n) {
        const float* wr = Wb + (size_t)n * D_MODEL;
        float s = 0.f;
#pragma unroll
        for (int j = 0; j < 16; ++j) s += xv[j] * wr[lane + 64 * j];
#pragma unroll
        for (int off = 32; off; off >>= 1) s += __shfl_xor(s, off);
        if (lane == 0) beta[(size_t)wave * NHEAD + n] = 2.f / (1.f + expf(-s));
    }
}

// ---------------------------------------------------------------------------
// L2-normalize q and k per (row, head) over HEAD_DIM=64.
// ---------------------------------------------------------------------------
__global__ __launch_bounds__(256) void norm_qk(float* __restrict__ Q,
                                               float* __restrict__ Kp) {
    const int TOT = ROWS * NHEAD;
    int wave = blockIdx.x * 4 + (threadIdx.x >> 6);
    const int lane = threadIdx.x & 63;
    float* T = (wave < TOT) ? Q : Kp;
    int w = (wave < TOT) ? wave : wave - TOT;
    float* p = T + (size_t)(w >> 4) * D_MODEL + (size_t)(w & 15) * HEAD_DIM;
    float v = p[lane];
    float ss = v * v;
#pragma unroll
    for (int off = 32; off; off >>= 1) ss += __shfl_xor(ss, off);
    p[lane] = v / (sqrtf(ss) + 1e-6f);
}

// ---------------------------------------------------------------------------
// Sequential delta-rule scan: R3 structure + DPP quad reductions (replaces
// ds_swizzle shuffles) + MT-row update hoisted before the barrier.
// ---------------------------------------------------------------------------
struct Tok { float q[16]; float k[16]; float kr, vr, bt; };

__global__ __launch_bounds__(256, 1) void scan_kernel(const float* __restrict__ Q,
                                                      const float* __restrict__ K,
                                                      const float* __restrict__ V,
                                                      const float* __restrict__ Bt,
                                                      float* __restrict__ Y) {
    __shared__ __align__(16) float Lq[2][CHUNK][HEAD_DIM];
    __shared__ __align__(16) float Lk[2][CHUNK][HEAD_DIM];
    __shared__ __align__(16) float Lv[2][CHUNK][HEAD_DIM];
    __shared__ __align__(16) float Lb[2][CHUNK];
    __shared__ __align__(16) float Ldelta[2][HEAD_DIM];

    const int b = blockIdx.x >> 4;
    const int n = blockIdx.x & 15;
    const int t = threadIdx.x;
    const int r = t >> 2;
    const int g = t & 3;
    const int w = t >> 6;
    const int lane = t & 63;
    const int bS = b * SEQ;
    const int nOff = n * HEAD_DIM;

    float Mrow[16], MTrow[16];
#pragma unroll
    for (int j = 0; j < 16; ++j) { Mrow[j] = 0.f; MTrow[j] = 0.f; }

    int par = 0;

    auto issue_loads = [&](int c, int db) {
        const int s0 = c * CHUNK;
        if (w < 3) {
            const float* T = (w == 0) ? Q : (w == 1) ? K : V;
            float* dst = (w == 0) ? &Lq[db][0][0] : (w == 1) ? &Lk[db][0][0] : &Lv[db][0][0];
#pragma unroll
            for (int i = 0; i < 16; ++i) {
                int f = i * 64 + lane;
                int tok = f >> 4, f4 = f & 15;
                const float* gp = T + (size_t)(bS + s0 + tok) * D_MODEL + nOff + f4 * 4;
                load_lds_16f(gp, dst + i * 256);
            }
        } else {
            const float* gp = Bt + (size_t)(bS + s0 + lane) * NHEAD + n;
            load_lds_4f(gp, &Lb[db][0]);
        }
    };

    auto prefetch = [&](Tok& T, int bf, int s) {
#pragma unroll
        for (int j = 0; j < 4; ++j) {
            float4 qv = *(const float4*)&Lq[bf][s][g * 16 + 4 * j];
            float4 kv = *(const float4*)&Lk[bf][s][g * 16 + 4 * j];
            T.q[4 * j + 0] = qv.x; T.q[4 * j + 1] = qv.y;
            T.q[4 * j + 2] = qv.z; T.q[4 * j + 3] = qv.w;
            T.k[4 * j + 0] = kv.x; T.k[4 * j + 1] = kv.y;
            T.k[4 * j + 2] = kv.z; T.k[4 * j + 3] = kv.w;
        }
        T.kr = Lk[bf][s][r];
        T.vr = Lv[bf][s][r];
        T.bt = Lb[bf][s];
    };

    auto step = [&](int sAbs, Tok& cur, Tok& nxt, int pfIdx, int bf) {
        float o0 = 0.f, o1 = 0.f, r0 = 0.f, r1 = 0.f;
#pragma unroll
        for (int j = 0; j < 8; ++j) { o0 += MTrow[j] * cur.q[j]; r0 += Mrow[j] * cur.k[j]; }
#pragma unroll
        for (int j = 8; j < 16; ++j) { o1 += MTrow[j] * cur.q[j]; r1 += Mrow[j] * cur.k[j]; }
        float o  = quad_add(o0 + o1);    // DPP: VALU-pipe quad reduction
        float rr = quad_add(r0 + r1);

        const float delta = cur.vr - rr;
        const float bd = cur.bt * delta;
        // MT update is purely local — do it before the barrier
#pragma unroll
        for (int j = 0; j < 16; ++j) MTrow[j] += bd * cur.k[j];

        if (g == 0) {
            Y[(size_t)(bS + sAbs) * D_MODEL + nOff + r] = o;   // pre-update out
            Ldelta[par][r] = delta;
        }
        sync_lds();   // lgkm-only: async chunk loads stay in flight

        float dl[16];
#pragma unroll
        for (int j = 0; j < 4; ++j) {
            float4 dv = *(const float4*)&Ldelta[par][g * 16 + 4 * j];
            dl[4 * j + 0] = dv.x; dl[4 * j + 1] = dv.y;
            dl[4 * j + 2] = dv.z; dl[4 * j + 3] = dv.w;
        }
        if (pfIdx >= 0) prefetch(nxt, bf, pfIdx);

        const float bk = cur.bt * cur.kr;
#pragma unroll
        for (int j = 0; j < 16; ++j) Mrow[j] += bk * dl[j];
        par ^= 1;
    };

    issue_loads(0, 0);
    __syncthreads();
    int buf = 0;
    Tok tA, tB;
    prefetch(tA, buf, 0);

    for (int c = 0; c < NCHUNK; ++c) {
        if (c < NCHUNK - 1) issue_loads(c + 1, buf ^ 1);
        const int s0 = c * CHUNK;
        for (int s = 0; s < CHUNK; s += 2) {
            step(s0 + s,     tA, tB, (s + 1 < CHUNK) ? s + 1 : -1, buf);
            step(s0 + s + 1, tB, tA, (s + 2 < CHUNK) ? s + 2 : -1, buf);
        }
        __syncthreads();
        if (c < NCHUNK - 1) {
            buf ^= 1;
            prefetch(tA, buf, 0);
        }
    }
}

// ---------------------------------------------------------------------------
// RMSNorm. SPLIT=1: write (hi,lo) bf16 for the final GEMM. SPLIT=0: fp32 in place.
// ---------------------------------------------------------------------------
template <int SPLIT>
__global__ __launch_bounds__(256) void rmsnorm_kernel(float* __restrict__ Y,
                                                      const float* __restrict__ w,
                                                      unsigned short* __restrict__ H,
                                                      unsigned short* __restrict__ L) {
    __shared__ float red[4];
    float* y = Y + (size_t)blockIdx.x * D_MODEL;
    const int t = threadIdx.x;
    const int wv = t >> 6, ln = t & 63;
    float4 v = ((float4*)y)[t];
    float ss = v.x * v.x + v.y * v.y + v.z * v.z + v.w * v.w;
#pragma unroll
    for (int off = 32; off; off >>= 1) ss += __shfl_xor(ss, off);
    if (ln == 0) red[wv] = ss;
    __syncthreads();
    float tot = red[0] + red[1] + red[2] + red[3];
    float inv = 1.f / sqrtf(tot * (1.f / D_MODEL) + 1e-6f);
    const float4 wv4 = ((const float4*)w)[t];
    v.x *= inv * wv4.x; v.y *= inv * wv4.y;
    v.z *= inv * wv4.z; v.w *= inv * wv4.w;
    if (SPLIT) {
        us4 h, l;
        h.x = f2bf(v.x); l.x = f2bf(v.x - bf2f(h.x));
        h.y = f2bf(v.y); l.y = f2bf(v.y - bf2f(h.y));
        h.z = f2bf(v.z); l.z = f2bf(v.z - bf2f(h.z));
        h.w = f2bf(v.w); l.w = f2bf(v.w - bf2f(h.w));
        size_t i = (size_t)blockIdx.x * 256 + t;
        ((us4*)H)[i] = h;
        ((us4*)L)[i] = l;
    } else {
        ((float4*)y)[t] = v;
    }
}

// ---------------------------------------------------------------------------
extern "C" void kernel_launch(void* const* d_in, const int* in_sizes, int n_in,
                              void* d_out, int out_size, void* d_ws, size_t ws_size,
                              hipStream_t stream) {
    const float* x     = (const float*)d_in[0];
    const float* Wq    = (const float*)d_in[1];
    const float* Wk    = (const float*)d_in[2];
    const float* Wv    = (const float*)d_in[3];
    const float* Wb    = (const float*)d_in[4];
    const float* Wo    = (const float*)d_in[5];
    const float* rms_w = (const float*)d_in[6];
    float* out = (float*)d_out;

    char* p = (char*)d_ws;
    float* Q  = (float*)p;  p += (size_t)RD * 4;
    float* Kp = (float*)p;  p += (size_t)RD * 4;
    float* Vp = (float*)p;  p += (size_t)RD * 4;
    float* Y  = (float*)p;  p += (size_t)RD * 4;
    float* Bt = (float*)p;  p += (size_t)32768 * 4;
    unsigned short* xh  = (unsigned short*)p;  p += (size_t)RD * 2;   // reused as Yh
    unsigned short* xl  = (unsigned short*)p;  p += (size_t)RD * 2;   // reused as Yl
    unsigned short* Wsh = (unsigned short*)p;  p += (size_t)WSZ * 2;
    unsigned short* Wsl = (unsigned short*)p;  p += (size_t)WSZ * 2;
    const size_t need_fast = (size_t)RD * 16 + 131072 + (size_t)RD * 4 + (size_t)WSZ * 4;
    const bool fast = ws_size >= need_fast;

    if (fast) {
        dim3 ggrid(D_MODEL / 64, ROWS / 128);   // (16,16) = 256 blocks
        split_kernel<<<RD / 4 / 256, 256, 0, stream>>>(x, xh, xl, RD / 4);
        split_kernel<<<WSZ / 4 / 256, 256, 0, stream>>>(Wq, Wsh, Wsl, WSZ / 4);
        gemm_bf16s<1><<<ggrid, 256, 0, stream>>>(xh, xl, Wsh, Wsl, Q, ROWS, D_MODEL, D_MODEL);
        split_kernel<<<WSZ / 4 / 256, 256, 0, stream>>>(Wk, Wsh, Wsl, WSZ / 4);
        gemm_bf16s<1><<<ggrid, 256, 0, stream>>>(xh, xl, Wsh, Wsl, Kp, ROWS, D_MODEL, D_MODEL);
        split_kernel<<<WSZ / 4 / 256, 256, 0, stream>>>(Wv, Wsh, Wsl, WSZ / 4);
        gemm_bf16s<1><<<ggrid, 256, 0, stream>>>(xh, xl, Wsh, Wsl, Vp, ROWS, D_MODEL, D_MODEL);
        beta_kernel<<<ROWS / 4, 256, 0, stream>>>(x, Wb, Bt);
        norm_qk<<<2 * ROWS * NHEAD / 4, 256, 0, stream>>>(Q, Kp);
        scan_kernel<<<BATCH * NHEAD, 256, 0, stream>>>(Q, Kp, Vp, Bt, Y);
        rmsnorm_kernel<1><<<ROWS, 256, 0, stream>>>(Y, rms_w, xh, xl);   // Yh=xh, Yl=xl
        split_kernel<<<WSZ / 4 / 256, 256, 0, stream>>>(Wo, Wsh, Wsl, WSZ / 4);
        gemm_bf16s<0><<<ggrid, 256, 0, stream>>>(xh, xl, Wsh, Wsl, out, ROWS, D_MODEL, D_MODEL);
    } else {
        dim3 ggrid(D_MODEL / 128, ROWS / 128);  // (8,16)
        gemm_mfma<1><<<ggrid, 256, 0, stream>>>(x, Wq, Q, ROWS, D_MODEL, D_MODEL);
        gemm_mfma<1><<<ggrid, 256, 0, stream>>>(x, Wk, Kp, ROWS, D_MODEL, D_MODEL);
        gemm_mfma<1><<<ggrid, 256, 0, stream>>>(x, Wv, Vp, ROWS, D_MODEL, D_MODEL);
        beta_kernel<<<ROWS / 4, 256, 0, stream>>>(x, Wb, Bt);
        norm_qk<<<2 * ROWS * NHEAD / 4, 256, 0, stream>>>(Q, Kp);
        scan_kernel<<<BATCH * NHEAD, 256, 0, stream>>>(Q, Kp, Vp, Bt, Y);
        rmsnorm_kernel<0><<<ROWS, 256, 0, stream>>>(Y, rms_w, nullptr, nullptr);
        gemm_mfma<0><<<ggrid, 256, 0, stream>>>(Y, Wo, out, ROWS, D_MODEL, D_MODEL);
    }
}